// Round 1
// baseline (43.288 us; speedup 1.0000x reference)
//
#include <hip/hip_runtime.h>
#include <hip/hip_bf16.h>

// Problem constants (from reference setup_inputs):
//   B=64, S=512, DB=768, DW=100, W=512
//   bert_x:   [B, S, DB]   float32
//   w2v:      [B, W, DW]   float32
//   mappings: [B, S-1]     int32
//   out:      [B, S, DB+DW]=[64,512,868] float32
// Semantics: row 0 of each batch is zero. Row r (1..S-1) is
//   [bert_x[b,r,:], w2v[b, mappings[b,r-1], :]] if all mappings[b,0..r-1] != -1
//   else zeros.

#define B_   64
#define S_   512
#define SM1_ 511
#define DB_  768
#define DW_  100
#define DOUT_ 868            // DB+DW
#define DOUT4_ 217           // DOUT/4
#define DB4_  192            // DB/4
#define W_   512

__global__ void first_invalid_kernel(const int* __restrict__ mappings,
                                     int* __restrict__ firstinv) {
    const int b = blockIdx.x;
    __shared__ int s_min;
    if (threadIdx.x == 0) s_min = SM1_;
    __syncthreads();
    for (int i = threadIdx.x; i < SM1_; i += blockDim.x) {
        if (mappings[b * SM1_ + i] == -1) atomicMin(&s_min, i);
    }
    __syncthreads();
    if (threadIdx.x == 0) firstinv[b] = s_min;
}

__global__ void fuse_rows_kernel(const float* __restrict__ bert_x,
                                 const float* __restrict__ w2v,
                                 const int* __restrict__ mappings,
                                 const int* __restrict__ firstinv,
                                 float* __restrict__ out) {
    const int row = blockIdx.x;          // b*S + r
    const int b = row >> 9;              // S = 512
    const int r = row & (S_ - 1);
    const int tid = threadIdx.x;         // 0..255
    float4* orow = reinterpret_cast<float4*>(out + (size_t)row * DOUT_);

    bool valid = false;
    if (r != 0) {
        valid = (r - 1) < firstinv[b];
    }
    if (!valid) {
        if (tid < DOUT4_) orow[tid] = make_float4(0.f, 0.f, 0.f, 0.f);
        return;
    }

    if (tid < DB4_) {
        const float4* brow = reinterpret_cast<const float4*>(
            bert_x + ((size_t)b * S_ + r) * DB_);
        orow[tid] = brow[tid];
    } else if (tid < DOUT4_) {
        int w = mappings[b * SM1_ + (r - 1)];
        if (w < 0) w = 0;  // clip (valid rows can't be -1, but match reference)
        const float4* wrow = reinterpret_cast<const float4*>(
            w2v + ((size_t)b * W_ + w) * DW_);
        orow[tid] = wrow[tid - DB4_];
    }
}

extern "C" void kernel_launch(void* const* d_in, const int* in_sizes, int n_in,
                              void* d_out, int out_size, void* d_ws, size_t ws_size,
                              hipStream_t stream) {
    const float* bert_x = (const float*)d_in[0];
    const float* w2v    = (const float*)d_in[1];
    const int* mappings = (const int*)d_in[2];
    float* out = (float*)d_out;
    int* firstinv = (int*)d_ws;   // 64 ints

    first_invalid_kernel<<<B_, 512, 0, stream>>>(mappings, firstinv);
    fuse_rows_kernel<<<B_ * S_, 256, 0, stream>>>(bert_x, w2v, mappings, firstinv, out);
}

// Round 2
// 40.386 us; speedup vs baseline: 1.0719x; 1.0719x over previous
//
#include <hip/hip_runtime.h>
#include <hip/hip_bf16.h>

// Problem constants (from reference setup_inputs):
//   B=64, S=512, DB=768, DW=100, W=512
//   bert_x:   [B, S, DB]   float32
//   w2v:      [B, W, DW]   float32
//   mappings: [B, S-1]     int32
//   out:      [B, S, DB+DW]=[64,512,868] float32
// Semantics: row 0 of each batch is zero. Row r (1..S-1) is
//   [bert_x[b,r,:], w2v[b, mappings[b,r-1], :]] if all mappings[b,0..r-1] != -1
//   else zeros.
//
// Single fused kernel: each block owns 8 rows of one batch and redundantly
// recomputes the batch's first-invalid mapping index (2 KB scan, L1/L2-hot,
// no atomics fire when no -1 present) — removes the separate reduction
// kernel and its graph-node serialization (~5 us).

#define B_    64
#define S_    512
#define SM1_  511
#define DB_   768
#define DW_   100
#define DOUT_ 868            // DB+DW
#define DOUT4_ 217           // DOUT/4
#define DB4_  192            // DB/4
#define W_    512
#define ROWS_PER_BLK_ 8      // S_/ROWS_PER_BLK_ chunks per batch

__global__ __launch_bounds__(256) void fused_fuse_rows_kernel(
        const float* __restrict__ bert_x,
        const float* __restrict__ w2v,
        const int* __restrict__ mappings,
        float* __restrict__ out) {
    const int blk   = blockIdx.x;        // b * (S/ROWS_PER_BLK) + chunk
    const int b     = blk >> 6;          // 64 chunks per batch
    const int chunk = blk & 63;
    const int r0    = chunk * ROWS_PER_BLK_;
    const int tid   = threadIdx.x;       // 0..255

    // --- redundant per-block first-invalid scan (batch-local, 2 KB) ---
    __shared__ int s_min;
    if (tid == 0) s_min = SM1_;
    __syncthreads();
    const int* __restrict__ mrow = mappings + b * SM1_;
    #pragma unroll
    for (int i = tid; i < SM1_; i += 256) {
        if (mrow[i] == -1) atomicMin(&s_min, i);
    }
    __syncthreads();
    const int fi = s_min;                // rows 1..fi are valid (r-1 < fi)

    // --- copy / zero 8 rows ---
    const float4* __restrict__ bbase = reinterpret_cast<const float4*>(
        bert_x + (size_t)b * S_ * DB_);
    const float4* __restrict__ wbase = reinterpret_cast<const float4*>(
        w2v + (size_t)b * W_ * DW_);
    float4* __restrict__ obase = reinterpret_cast<float4*>(
        out + (size_t)b * S_ * DOUT_);

    #pragma unroll
    for (int rr = 0; rr < ROWS_PER_BLK_; ++rr) {
        const int r = r0 + rr;
        float4* orow = obase + (size_t)r * DOUT4_;
        const bool valid = (r != 0) && ((r - 1) < fi);
        if (!valid) {
            if (tid < DOUT4_) orow[tid] = make_float4(0.f, 0.f, 0.f, 0.f);
        } else if (tid < DB4_) {
            orow[tid] = bbase[(size_t)r * DB4_ + tid];
        } else if (tid < DOUT4_) {
            int w = mrow[r - 1];
            if (w < 0) w = 0;            // match reference clip (unreachable for valid rows)
            orow[tid] = wbase[(size_t)w * (DW_ / 4) + (tid - DB4_)];
        }
    }
}

extern "C" void kernel_launch(void* const* d_in, const int* in_sizes, int n_in,
                              void* d_out, int out_size, void* d_ws, size_t ws_size,
                              hipStream_t stream) {
    const float* bert_x = (const float*)d_in[0];
    const float* w2v    = (const float*)d_in[1];
    const int* mappings = (const int*)d_in[2];
    float* out = (float*)d_out;

    fused_fuse_rows_kernel<<<B_ * (S_ / ROWS_PER_BLK_), 256, 0, stream>>>(
        bert_x, w2v, mappings, out);
}